// Round 12
// baseline (90.331 us; speedup 1.0000x reference)
//
#include <hip/hip_runtime.h>
#include <math.h>

// ---- problem dims ----
#define BB 8
#define SS 512
#define NEDGE 2048
#define MAXN 4096
#define TYPED 16
#define MEMD 64
#define TENC 32
#define EEMB 128
#define OUTD 64
#define MSG 304      // 16+64+64+32+128
#define INGNN 192    // 128+64
#define EDIM 160     // 32+128
#define BN 8192      // B*N
#define BE 16384     // B*E
#define QK_CH 96
#define EE_CH 80
#define GST 20       // gru LDS row stride (80B: 16B-aligned, tolerable write aliasing)

__device__ __forceinline__ float sigmoidf(float x){ return 1.f/(1.f + expf(-x)); }

// ---- init: zero accumulator span (float4), first_pos=INT_MAX, W transposes ----
__global__ void k_init(float* zero_base, int n_zero, int* first_pos,
                       const float* Wq, const float* Wk, const float* Wv,
                       const float* Wskip, const float* We,
                       const float* bq, const float* bk,
                       const float* bv, const float* bskip,
                       float* WcatT, float* WeT, float* bcat){
  int i = blockIdx.x*blockDim.x + threadIdx.x;
  int stride = gridDim.x*blockDim.x;
  float4* z4 = (float4*)zero_base;
  int n4 = n_zero >> 2;
  float4 zero = {0.f,0.f,0.f,0.f};
  for (int t=i; t<n4; t+=stride) z4[t] = zero;
  for (int t=i; t<MAXN; t+=stride) first_pos[t] = 0x7FFFFFFF;
  int j = i;
  if (j < 4*64*192){
    int o = j/(64*192); int rem = j%(64*192); int q=rem/192, k=rem%192;
    const float* W = (o==0)?Wq:(o==1)?Wk:(o==2)?Wv:Wskip;
    WcatT[k*256 + o*64 + q] = W[rem];
  } else {
    j -= 4*64*192;
    if (j < 64*EDIM){ int q=j/EDIM, k=j%EDIM; WeT[k*64+q] = We[j]; }
    else {
      j -= 64*EDIM;
      if (j < 256){
        const float* b = (j<64)?bq:(j<128)?bk:(j<192)?bv:bskip;
        bcat[j] = b[j&63];
      }
    }
  }
}

// ---- merged: edge GEMM (blocks 0..255) || batch-0 messages (256..767) ||
//      first-pos/presence (768..799). Edge work hides under light scatter work. ----
__global__ __launch_bounds__(256) void k_msg_edge(
    const int* ev_type, const int* src_ids, const float* src_mask,
    const int* dst_ids, const float* dst_mask, const int* ev_edge,
    const float* ev_emb, const float* ev_ts, const float* memory,
    const float* last_update, const float* type_emb,
    const float* time_w, const float* time_b,
    float* agg_src, float* agg_dst, int* cnt_src, int* cnt_dst,
    const int* node_ids, int* first_pos, int* ps, int* pd,
    const int* edge_ids, const float* edge_ts,
    const float* edge_features, const float* WeT, float* ebuf){
  __shared__ float smem[EE_CH*68 + EE_CH*64];   // 42.2 KB (edge blocks only)
  int tid = threadIdx.x;
  int bb = blockIdx.x;
  if (bb < 256){
    // ---- edge attr GEMM: 64 edges/block ----
    float* ea_t = smem;               // [EE_CH][68]
    float* wls  = smem + EE_CH*68;    // [EE_CH][64]
    int ebase = bb * 64;
    int ee = tid & 63, qq = tid >> 6;
    int j = ebase + ee;
    int eid = edge_ids[j];
    float rel = edge_ts[j] - last_update[eid];
    int tr = tid >> 4, tc = tid & 15;
    float4 acc[4];
    #pragma unroll
    for (int i=0;i<4;i++) acc[i] = (float4){0.f,0.f,0.f,0.f};
    for (int kc = 0; kc < 2; kc++){
      #pragma unroll 5
      for (int m = 0; m < 20; m++){
        int kk = qq*20 + m;
        int k  = kc*EE_CH + kk;
        float v = (k < TENC) ? cosf(rel*time_w[k] + time_b[k])
                             : edge_features[eid*EEMB + (k - TENC)];
        ea_t[kk*68 + ee] = v;
      }
      #pragma unroll
      for (int it = 0; it < 5; it++){
        int idx = tid + it*256;
        int kk = idx >> 4, c4 = (idx & 15) * 4;
        *(float4*)&wls[kk*64 + c4] = *(const float4*)&WeT[(kc*EE_CH + kk)*64 + c4];
      }
      __syncthreads();
      #pragma unroll 4
      for (int kk = 0; kk < EE_CH; kk++){
        float4 ev = *(const float4*)&ea_t[kk*68 + tr*4];
        float4 wv = *(const float4*)&wls[kk*64 + tc*4];
        acc[0].x += ev.x*wv.x; acc[0].y += ev.x*wv.y; acc[0].z += ev.x*wv.z; acc[0].w += ev.x*wv.w;
        acc[1].x += ev.y*wv.x; acc[1].y += ev.y*wv.y; acc[1].z += ev.y*wv.z; acc[1].w += ev.y*wv.w;
        acc[2].x += ev.z*wv.x; acc[2].y += ev.z*wv.y; acc[2].z += ev.z*wv.z; acc[2].w += ev.z*wv.w;
        acc[3].x += ev.w*wv.x; acc[3].y += ev.w*wv.y; acc[3].z += ev.w*wv.z; acc[3].w += ev.w*wv.w;
      }
      __syncthreads();
    }
    #pragma unroll
    for (int i=0;i<4;i++)
      *(float4*)&ebuf[(ebase + tr*4 + i)*OUTD + tc*4] = acc[i];
  } else if (bb < 768){
    // ---- batch-0 messages: one event per block ----
    int s = bb - 256;
    int et = ev_type[s];
    int sid = src_ids[s], did = dst_ids[s];
    float sm = src_mask[s], dm = dst_mask[s];
    float ts = ev_ts[s];
    float ns = (et >= 3) ? 1.f : 0.f;
    float ine = (et == 3 || et == 4) ? 1.f : 0.f;
    float rel = ts - last_update[ev_edge[s]] * dm;
    float tin = ts*ine + rel*dm;
    for (int d = tid; d < MSG; d += 256){
      float vs, vd;
      if (d < TYPED){ float t = type_emb[et*TYPED + d]; vs = t; vd = t; }
      else if (d < 80){ int c=d-16;  vs = memory[sid*MEMD+c]*sm; vd = memory[did*MEMD+c]*dm; }
      else if (d < 144){ int c=d-80; vs = memory[did*MEMD+c]*dm; vd = memory[sid*MEMD+c]*sm; }
      else if (d < 176){ int c=d-144; float ce = cosf(tin*time_w[c]+time_b[c])*ns; vs=ce; vd=ce; }
      else { float e = ev_emb[s*EEMB + (d-176)]; vs=e; vd=e; }
      atomicAdd(&agg_src[sid*MSG+d], vs*ns);
      atomicAdd(&agg_dst[did*MSG+d], vd*dm);
    }
    if (tid == 0){ atomicAdd(&cnt_src[sid], 1); atomicAdd(&cnt_dst[did], 1); }
  } else {
    int i = (bb - 768)*256 + tid;    // 32 blocks x 256 = 8192 = BN
    atomicMin(&first_pos[node_ids[i]], i);
    if (i < BB*SS){ ps[src_ids[i]] = 1; pd[dst_ids[i]] = 1; }
  }
}

// ---- GRU: 16 nodes/block, 256 blocks. Weights streamed row-major per output col;
//      x/h staged LDS-transposed (broadcast reads in compute phase). ----
__global__ __launch_bounds__(256) void k_gru(
    const float* agg_src, const float* agg_dst, const int* cnt_src, const int* cnt_dst,
    const int* ps, const int* pd, const float* memory,
    const float* w_ih, const float* w_hh, const float* b_ih, const float* b_hh,
    float* mem_new){
  __shared__ float xs_t[MSG*GST];     // [MSG][20]
  __shared__ float hs_t[MEMD*GST];    // [64][20]
  __shared__ float giL[16*192];
  __shared__ float ghL[16*192];
  __shared__ int   mode[16];
  __shared__ float rcnt[16];
  int tid = threadIdx.x;
  int base = blockIdx.x * 16;
  if (tid < 16){
    int n = base + tid;
    int m = pd[n] ? 2 : (ps[n] ? 1 : 0);
    mode[tid] = m;
    int c = (m==2) ? cnt_dst[n] : ((m==1) ? cnt_src[n] : 0);
    rcnt[tid] = 1.f / (float)max(c, 1);
  }
  __syncthreads();
  for (int idx = tid; idx < 16*MSG; idx += 256){
    int t = idx / MSG, k = idx - t*MSG;
    const float* agg = (mode[t]==2) ? agg_dst : agg_src;
    xs_t[k*GST + t] = agg[(base+t)*MSG + k] * rcnt[t];
  }
  for (int idx = tid; idx < 16*MEMD; idx += 256){
    int t = idx >> 6, k = idx & 63;
    hs_t[k*GST + t] = memory[(base+t)*MEMD + k];
  }
  __syncthreads();
  if (tid < 192){
    // gi = x @ w_ih^T + b_ih
    float4 A0={0,0,0,0}, A1={0,0,0,0}, A2={0,0,0,0}, A3={0,0,0,0};
    const float* wr = &w_ih[tid*MSG];
    #pragma unroll 2
    for (int k4 = 0; k4 < MSG; k4 += 4){
      float4 w4 = *(const float4*)&wr[k4];
      #pragma unroll
      for (int i = 0; i < 4; i++){
        float wc = (i==0)? w4.x : (i==1)? w4.y : (i==2)? w4.z : w4.w;
        const float* xb = &xs_t[(k4+i)*GST];
        float4 x0 = *(const float4*)&xb[0];
        float4 x1 = *(const float4*)&xb[4];
        float4 x2 = *(const float4*)&xb[8];
        float4 x3 = *(const float4*)&xb[12];
        A0.x += wc*x0.x; A0.y += wc*x0.y; A0.z += wc*x0.z; A0.w += wc*x0.w;
        A1.x += wc*x1.x; A1.y += wc*x1.y; A1.z += wc*x1.z; A1.w += wc*x1.w;
        A2.x += wc*x2.x; A2.y += wc*x2.y; A2.z += wc*x2.z; A2.w += wc*x2.w;
        A3.x += wc*x3.x; A3.y += wc*x3.y; A3.z += wc*x3.z; A3.w += wc*x3.w;
      }
    }
    float bi = b_ih[tid];
    giL[ 0*192+tid]=A0.x+bi; giL[ 1*192+tid]=A0.y+bi; giL[ 2*192+tid]=A0.z+bi; giL[ 3*192+tid]=A0.w+bi;
    giL[ 4*192+tid]=A1.x+bi; giL[ 5*192+tid]=A1.y+bi; giL[ 6*192+tid]=A1.z+bi; giL[ 7*192+tid]=A1.w+bi;
    giL[ 8*192+tid]=A2.x+bi; giL[ 9*192+tid]=A2.y+bi; giL[10*192+tid]=A2.z+bi; giL[11*192+tid]=A2.w+bi;
    giL[12*192+tid]=A3.x+bi; giL[13*192+tid]=A3.y+bi; giL[14*192+tid]=A3.z+bi; giL[15*192+tid]=A3.w+bi;
    // gh = h @ w_hh^T + b_hh
    float4 B0={0,0,0,0}, B1={0,0,0,0}, B2={0,0,0,0}, B3={0,0,0,0};
    const float* wh = &w_hh[tid*MEMD];
    #pragma unroll 2
    for (int k4 = 0; k4 < MEMD; k4 += 4){
      float4 w4 = *(const float4*)&wh[k4];
      #pragma unroll
      for (int i = 0; i < 4; i++){
        float wc = (i==0)? w4.x : (i==1)? w4.y : (i==2)? w4.z : w4.w;
        const float* xb = &hs_t[(k4+i)*GST];
        float4 x0 = *(const float4*)&xb[0];
        float4 x1 = *(const float4*)&xb[4];
        float4 x2 = *(const float4*)&xb[8];
        float4 x3 = *(const float4*)&xb[12];
        B0.x += wc*x0.x; B0.y += wc*x0.y; B0.z += wc*x0.z; B0.w += wc*x0.w;
        B1.x += wc*x1.x; B1.y += wc*x1.y; B1.z += wc*x1.z; B1.w += wc*x1.w;
        B2.x += wc*x2.x; B2.y += wc*x2.y; B2.z += wc*x2.z; B2.w += wc*x2.w;
        B3.x += wc*x3.x; B3.y += wc*x3.y; B3.z += wc*x3.z; B3.w += wc*x3.w;
      }
    }
    float bh = b_hh[tid];
    ghL[ 0*192+tid]=B0.x+bh; ghL[ 1*192+tid]=B0.y+bh; ghL[ 2*192+tid]=B0.z+bh; ghL[ 3*192+tid]=B0.w+bh;
    ghL[ 4*192+tid]=B1.x+bh; ghL[ 5*192+tid]=B1.y+bh; ghL[ 6*192+tid]=B1.z+bh; ghL[ 7*192+tid]=B1.w+bh;
    ghL[ 8*192+tid]=B2.x+bh; ghL[ 9*192+tid]=B2.y+bh; ghL[10*192+tid]=B2.z+bh; ghL[11*192+tid]=B2.w+bh;
    ghL[12*192+tid]=B3.x+bh; ghL[13*192+tid]=B3.y+bh; ghL[14*192+tid]=B3.z+bh; ghL[15*192+tid]=B3.w+bh;
  }
  __syncthreads();
  int cw = tid >> 6, col = tid & 63;
  for (int t = cw; t < 16; t += 4){
    float h = hs_t[col*GST + t];
    float outv;
    int m = mode[t];
    if (m == 0) outv = h;
    else {
      float r  = sigmoidf(giL[t*192+col]      + ghL[t*192+col]);
      float z  = sigmoidf(giL[t*192+64+col]   + ghL[t*192+64+col]);
      float ng = tanhf  (giL[t*192+128+col] + r*ghL[t*192+128+col]);
      outv = (1.f - z)*ng + z*h;
    }
    mem_new[(base+t)*MEMD + col] = outv;
  }
}

// ---- qkvs GEMM (LDS-resident, 512 blocks): skip written directly to d_out ----
__global__ __launch_bounds__(256) void k_qkvs(const int* node_ids, const float* node_feat,
                                              const float* mem_new, const float* WcatT,
                                              const float* bcat, float* qbuf, float* kbuf,
                                              float* vbuf, float* outbuf){
  __shared__ float smem[QK_CH*68 + QK_CH*64];   // 50.7 KB
  float* xs_t = smem;
  float* wls  = smem + QK_CH*68;
  int tid = threadIdx.x;
  int rg = blockIdx.x >> 2, cgx = blockIdx.x & 3;
  int rbase = rg * 64;
  int rr = tid & 63, qq = tid >> 6;
  int nid = node_ids[rbase + rr];
  int tr = tid >> 4, tc = tid & 15;
  float4 acc[4];
  #pragma unroll
  for (int i=0;i<4;i++) acc[i] = (float4){0.f,0.f,0.f,0.f};
  for (int kc = 0; kc < 2; kc++){
    #pragma unroll 6
    for (int m = 0; m < 24; m++){
      int kk = qq*24 + m;
      int k  = kc*QK_CH + kk;
      float v = (k < EEMB) ? node_feat[nid*EEMB + k] : mem_new[nid*MEMD + (k-EEMB)];
      xs_t[kk*68 + rr] = v;
    }
    #pragma unroll
    for (int it = 0; it < 6; it++){
      int idx = tid + it*256;
      int kk = idx >> 4, c4 = (idx & 15) * 4;
      *(float4*)&wls[kk*64 + c4] = *(const float4*)&WcatT[(kc*QK_CH + kk)*256 + cgx*64 + c4];
    }
    __syncthreads();
    #pragma unroll 4
    for (int kk = 0; kk < QK_CH; kk++){
      float4 xv = *(const float4*)&xs_t[kk*68 + tr*4];
      float4 wv = *(const float4*)&wls[kk*64 + tc*4];
      acc[0].x += xv.x*wv.x; acc[0].y += xv.x*wv.y; acc[0].z += xv.x*wv.z; acc[0].w += xv.x*wv.w;
      acc[1].x += xv.y*wv.x; acc[1].y += xv.y*wv.y; acc[1].z += xv.y*wv.z; acc[1].w += xv.y*wv.w;
      acc[2].x += xv.z*wv.x; acc[2].y += xv.z*wv.y; acc[2].z += xv.z*wv.z; acc[2].w += xv.z*wv.w;
      acc[3].x += xv.w*wv.x; acc[3].y += xv.w*wv.y; acc[3].z += xv.w*wv.z; acc[3].w += xv.w*wv.w;
    }
    __syncthreads();
  }
  float4 b4 = *(const float4*)&bcat[cgx*64 + tc*4];
  float* dst = (cgx==0)? qbuf : (cgx==1)? kbuf : (cgx==2)? vbuf : outbuf;
  #pragma unroll
  for (int i=0;i<4;i++){
    float4 o = {acc[i].x+b4.x, acc[i].y+b4.y, acc[i].z+b4.z, acc[i].w+b4.w};
    *(float4*)&dst[(rbase + tr*4 + i)*OUTD + tc*4] = o;
  }
}

// ---- single-pass attention: score -> exp -> accumulate unnormalized num/den.
//      1024 blocks x 4 waves x 4 edges. Row-0 -> per-block partials (no chain). ----
__global__ __launch_bounds__(256) void k_att(const int* edge_index, const int* first_pos,
                                             const float* qbuf, const float* kbuf,
                                             const float* vbuf, const float* ebuf,
                                             float* num, float* den,
                                             float* out0part, float* den0part){
  __shared__ float acc0[4][64];
  __shared__ float sdw[4];
  int tid = threadIdx.x;
  int w = tid >> 6, c = tid & 63;
  float a0 = 0.f, pden = 0.f;
  #pragma unroll
  for (int u = 0; u < 4; u++){
    int j = blockIdx.x*16 + w*4 + u;
    int b = j >> 11, e = j & (NEDGE-1);
    int vsrc = edge_index[b*2*NEDGE + e];
    int vtgt = edge_index[b*2*NEDGE + NEDGE + e];
    int fs = first_pos[vsrc]; if (fs == 0x7FFFFFFF) fs = 0;
    int ft = first_pos[vtgt]; if (ft == 0x7FFFFFFF) ft = 0;
    float ej = ebuf[j*OUTD + c];
    float partial = qbuf[ft*OUTD + c] * (kbuf[fs*OUTD + c] + ej);
    #pragma unroll
    for (int off = 32; off > 0; off >>= 1) partial += __shfl_down(partial, off, 64);
    float sc = __shfl(partial, 0, 64);
    float pe = expf(sc * 0.125f);       // softmax shift-invariant; scores O(0.1)
    float ve = vbuf[fs*OUTD + c] + ej;
    if (ft == 0){ a0 += pe*ve; pden += pe; }              // wave-uniform branch
    else {
      atomicAdd(&num[ft*OUTD + c], pe*ve);
      if (c == 0) atomicAdd(&den[ft], pe);
    }
  }
  acc0[w][c] = a0;
  if (c == 0) sdw[w] = pden;
  __syncthreads();
  if (w == 0){
    out0part[blockIdx.x*64 + c] = acc0[0][c]+acc0[1][c]+acc0[2][c]+acc0[3][c];
    if (c == 0) den0part[blockIdx.x] = sdw[0]+sdw[1]+sdw[2]+sdw[3];
  }
}

// ---- normalize: out += num/den (rows 1..); block 512 reduces row-0 partials ----
__global__ __launch_bounds__(256) void k_norm(const float* num, const float* den,
                                              const float* out0part, const float* den0part,
                                              float* out){
  int tid = threadIdx.x;
  if (blockIdx.x < 512){
    int r = blockIdx.x*16 + (tid >> 4);
    int c4 = (tid & 15) * 4;
    if (r > 0){
      float d = den[r];
      if (d > 0.f){
        float rinv = 1.f / d;
        float4 n4 = *(const float4*)&num[r*64 + c4];
        float4 o4 = *(const float4*)&out[r*64 + c4];
        o4.x += n4.x*rinv; o4.y += n4.y*rinv; o4.z += n4.z*rinv; o4.w += n4.w*rinv;
        *(float4*)&out[r*64 + c4] = o4;
      }
    }
  } else {
    __shared__ float part[4][64];
    __shared__ float dred[4];
    __shared__ float s_den0;
    int g = tid >> 6, c = tid & 63;
    float s = 0.f;
    for (int j = g*256; j < g*256 + 256; j++) s += out0part[j*64 + c];
    part[g][c] = s;
    float dd = den0part[tid] + den0part[tid+256] + den0part[tid+512] + den0part[tid+768];
    #pragma unroll
    for (int off = 32; off > 0; off >>= 1) dd += __shfl_down(dd, off, 64);
    if (c == 0) dred[g] = dd;
    __syncthreads();
    if (tid == 0) s_den0 = dred[0]+dred[1]+dred[2]+dred[3];
    __syncthreads();
    if (g == 0){
      float den0 = s_den0;
      if (den0 > 0.f)
        out[c] += (part[0][c]+part[1][c]+part[2][c]+part[3][c]) / den0;
    }
  }
}

extern "C" void kernel_launch(void* const* d_in, const int* in_sizes, int n_in,
                              void* d_out, int out_size, void* d_ws, size_t ws_size,
                              hipStream_t stream){
  const int*   ev_type      = (const int*)  d_in[0];
  const int*   src_ids      = (const int*)  d_in[1];
  const float* src_mask     = (const float*)d_in[2];
  const int*   dst_ids      = (const int*)  d_in[3];
  const float* dst_mask     = (const float*)d_in[4];
  const int*   ev_edge      = (const int*)  d_in[5];
  const float* ev_emb       = (const float*)d_in[6];
  const float* ev_ts        = (const float*)d_in[7];
  const int*   node_ids     = (const int*)  d_in[8];
  const int*   edge_ids     = (const int*)  d_in[9];
  const int*   edge_index   = (const int*)  d_in[10];
  const float* edge_ts      = (const float*)d_in[11];
  const float* memory       = (const float*)d_in[12];
  const float* last_update  = (const float*)d_in[13];
  const float* node_feat    = (const float*)d_in[14];
  const float* edge_feat    = (const float*)d_in[15];
  const float* type_emb     = (const float*)d_in[16];
  const float* time_w       = (const float*)d_in[17];
  const float* time_b       = (const float*)d_in[18];
  const float* gru_w_ih     = (const float*)d_in[19];
  const float* gru_w_hh     = (const float*)d_in[20];
  const float* gru_b_ih     = (const float*)d_in[21];
  const float* gru_b_hh     = (const float*)d_in[22];
  const float* Wq  = (const float*)d_in[23]; const float* bq    = (const float*)d_in[24];
  const float* Wk  = (const float*)d_in[25]; const float* bk    = (const float*)d_in[26];
  const float* Wv  = (const float*)d_in[27]; const float* bv    = (const float*)d_in[28];
  const float* We  = (const float*)d_in[29];
  const float* Wsk = (const float*)d_in[30]; const float* bskip = (const float*)d_in[31];
  float* out = (float*)d_out;

  float* ws = (float*)d_ws;
  size_t off = 0;
  // --- zeroed span (accumulators) ---
  float* agg_src = ws + off; off += (size_t)MAXN*MSG;
  float* agg_dst = ws + off; off += (size_t)MAXN*MSG;
  int* cnt_src   = (int*)(ws + off); off += MAXN;
  int* cnt_dst   = (int*)(ws + off); off += MAXN;
  int* present_s = (int*)(ws + off); off += MAXN;
  int* present_d = (int*)(ws + off); off += MAXN;
  float* den     = ws + off; off += BN;
  float* num     = ws + off; off += (size_t)BN*OUTD;
  int n_zero = (int)off;
  // --- rest (fully overwritten each call) ---
  int* first_pos = (int*)(ws + off); off += MAXN;
  float* mem_new = ws + off; off += (size_t)MAXN*MEMD;
  float* qbuf    = ws + off; off += (size_t)BN*OUTD;
  float* kbuf    = ws + off; off += (size_t)BN*OUTD;
  float* vbuf    = ws + off; off += (size_t)BN*OUTD;
  float* ebuf    = ws + off; off += (size_t)BE*OUTD;
  float* den0part= ws + off; off += 1024;
  float* out0part= ws + off; off += 1024*64;
  float* WcatT   = ws + off; off += (size_t)INGNN*256;
  float* WeT     = ws + off; off += (size_t)EDIM*64;
  float* bcat    = ws + off; off += 256;

  k_init<<<2048, 256, 0, stream>>>(ws, n_zero, first_pos,
                                   Wq, Wk, Wv, Wsk, We, bq, bk, bv, bskip,
                                   WcatT, WeT, bcat);
  k_msg_edge<<<800, 256, 0, stream>>>(
      ev_type, src_ids, src_mask, dst_ids, dst_mask, ev_edge,
      ev_emb, ev_ts, memory, last_update, type_emb, time_w, time_b,
      agg_src, agg_dst, cnt_src, cnt_dst,
      node_ids, first_pos, present_s, present_d,
      edge_ids, edge_ts, edge_feat, WeT, ebuf);
  k_gru<<<256, 256, 0, stream>>>(agg_src, agg_dst, cnt_src, cnt_dst,
                                 present_s, present_d, memory,
                                 gru_w_ih, gru_w_hh, gru_b_ih, gru_b_hh, mem_new);
  k_qkvs<<<512, 256, 0, stream>>>(node_ids, node_feat, mem_new, WcatT, bcat,
                                  qbuf, kbuf, vbuf, out);
  k_att<<<1024, 256, 0, stream>>>(edge_index, first_pos, qbuf, kbuf, vbuf, ebuf,
                                  num, den, out0part, den0part);
  k_norm<<<513, 256, 0, stream>>>(num, den, out0part, den0part, out);
}

// Round 13
// 79.000 us; speedup vs baseline: 1.1434x; 1.1434x over previous
//
#include <hip/hip_runtime.h>
#include <math.h>

// ---- problem dims ----
#define BB 8
#define SS 512
#define NEDGE 2048
#define MAXN 4096
#define TYPED 16
#define MEMD 64
#define TENC 32
#define EEMB 128
#define OUTD 64
#define MSG 304      // 16+64+64+32+128
#define INGNN 192    // 128+64
#define EDIM 160     // 32+128
#define BN 8192      // B*N
#define BE 16384     // B*E
#define QK_CH 96
#define EE_CH 80

__device__ __forceinline__ float sigmoidf(float x){ return 1.f/(1.f + expf(-x)); }

// ---- init: zero accumulator span (float4), first_pos=INT_MAX, W transposes ----
__global__ void k_init(float* zero_base, int n_zero, int* first_pos,
                       const float* Wq, const float* Wk, const float* Wv,
                       const float* Wskip, const float* We,
                       const float* bq, const float* bk,
                       const float* bv, const float* bskip,
                       float* WcatT, float* WeT, float* bcat){
  int i = blockIdx.x*blockDim.x + threadIdx.x;
  int stride = gridDim.x*blockDim.x;
  float4* z4 = (float4*)zero_base;
  int n4 = n_zero >> 2;
  float4 zero = {0.f,0.f,0.f,0.f};
  for (int t=i; t<n4; t+=stride) z4[t] = zero;
  for (int t=i; t<MAXN; t+=stride) first_pos[t] = 0x7FFFFFFF;
  int j = i;
  if (j < 4*64*192){
    int o = j/(64*192); int rem = j%(64*192); int q=rem/192, k=rem%192;
    const float* W = (o==0)?Wq:(o==1)?Wk:(o==2)?Wv:Wskip;
    WcatT[k*256 + o*64 + q] = W[rem];
  } else {
    j -= 4*64*192;
    if (j < 64*EDIM){ int q=j/EDIM, k=j%EDIM; WeT[k*64+q] = We[j]; }
    else {
      j -= 64*EDIM;
      if (j < 256){
        const float* b = (j<64)?bq:(j<128)?bk:(j<192)?bv:bskip;
        bcat[j] = b[j&63];
      }
    }
  }
}

// ---- fused: messages for batch 0 (blocks < SS) + first-pos/presence (rest) ----
__global__ void k_msg_first(const int* ev_type, const int* src_ids, const float* src_mask,
                            const int* dst_ids, const float* dst_mask, const int* ev_edge,
                            const float* ev_emb, const float* ev_ts, const float* memory,
                            const float* last_update, const float* type_emb,
                            const float* time_w, const float* time_b,
                            float* agg_src, float* agg_dst, int* cnt_src, int* cnt_dst,
                            const int* node_ids, int* first_pos, int* ps, int* pd){
  int bb = blockIdx.x;
  if (bb < SS){
    int s = bb;
    int et = ev_type[s];
    int sid = src_ids[s], did = dst_ids[s];
    float sm = src_mask[s], dm = dst_mask[s];
    float ts = ev_ts[s];
    float ns = (et >= 3) ? 1.f : 0.f;
    float ine = (et == 3 || et == 4) ? 1.f : 0.f;
    float rel = ts - last_update[ev_edge[s]] * dm;
    float tin = ts*ine + rel*dm;
    int d = threadIdx.x;
    if (d < MSG){
      float vs, vd;
      if (d < TYPED){ float t = type_emb[et*TYPED + d]; vs = t; vd = t; }
      else if (d < 80){ int c=d-16;  vs = memory[sid*MEMD+c]*sm; vd = memory[did*MEMD+c]*dm; }
      else if (d < 144){ int c=d-80; vs = memory[did*MEMD+c]*dm; vd = memory[sid*MEMD+c]*sm; }
      else if (d < 176){ int c=d-144; float ce = cosf(tin*time_w[c]+time_b[c])*ns; vs=ce; vd=ce; }
      else { float e = ev_emb[s*EEMB + (d-176)]; vs=e; vd=e; }
      atomicAdd(&agg_src[sid*MSG+d], vs*ns);
      atomicAdd(&agg_dst[did*MSG+d], vd*dm);
    }
    if (d == MSG){ atomicAdd(&cnt_src[sid], 1); atomicAdd(&cnt_dst[did], 1); }
  } else {
    int i = (bb - SS)*320 + threadIdx.x;
    if (i < BN) atomicMin(&first_pos[node_ids[i]], i);
    if (i < BB*SS){ ps[src_ids[i]] = 1; pd[dst_ids[i]] = 1; }
  }
}

// ---- fused GRU (blocks 0..511) || edge GEMM (blocks 512..767): independent work,
//      both branches LDS-heavy so the shared worst-case LDS budget costs nothing ----
__global__ __launch_bounds__(256) void k_gru_edge(
    const float* agg_src, const float* agg_dst, const int* cnt_src, const int* cnt_dst,
    const int* ps, const int* pd, const float* memory,
    const float* w_ih, const float* w_hh, const float* b_ih, const float* b_hh,
    float* mem_new,
    const int* edge_ids, const float* edge_ts, const float* last_update,
    const float* edge_features, const float* time_w, const float* time_b,
    const float* WeT, float* ebuf){
  __shared__ float smem[EE_CH*68 + EE_CH*64];   // 10560 floats = 42.2 KB (max of both uses)
  int tid = threadIdx.x;
  if (blockIdx.x < 512){
    // ---- GRU: 8 nodes/block ----
    float* xs_t = smem;                 // [MSG][12]
    float* hs_t = smem + 3648;          // [MEMD][12]
    float* giL  = smem + 4416;          // [8][192]
    float* ghL  = smem + 5952;          // [8][192]
    int*   mode = (int*)(smem + 7488);  // [8]
    float* rcnt = smem + 7496;          // [8]
    int base = blockIdx.x * 8;
    if (tid < 8){
      int n = base + tid;
      int m = pd[n] ? 2 : (ps[n] ? 1 : 0);
      mode[tid] = m;
      int c = (m==2) ? cnt_dst[n] : ((m==1) ? cnt_src[n] : 0);
      rcnt[tid] = 1.f / (float)max(c, 1);
    }
    __syncthreads();
    for (int idx = tid; idx < 8*MSG; idx += 256){
      int t = idx / MSG, k = idx - t*MSG;
      const float* agg = (mode[t]==2) ? agg_dst : agg_src;
      xs_t[k*12 + t] = agg[(base+t)*MSG + k] * rcnt[t];
    }
    for (int idx = tid; idx < 8*MEMD; idx += 256){
      int t = idx / MEMD, k = idx - t*MEMD;
      hs_t[k*12 + t] = memory[(base+t)*MEMD + k];
    }
    __syncthreads();
    if (tid < 192){
      float4 a0={0,0,0,0}, a1={0,0,0,0};
      const float* wr = &w_ih[tid*MSG];
      #pragma unroll 2
      for (int k4 = 0; k4 < MSG; k4 += 4){
        float4 w4 = *(const float4*)&wr[k4];
        float4 x0, x1;
        x0 = *(const float4*)&xs_t[(k4+0)*12]; x1 = *(const float4*)&xs_t[(k4+0)*12+4];
        a0.x += w4.x*x0.x; a0.y += w4.x*x0.y; a0.z += w4.x*x0.z; a0.w += w4.x*x0.w;
        a1.x += w4.x*x1.x; a1.y += w4.x*x1.y; a1.z += w4.x*x1.z; a1.w += w4.x*x1.w;
        x0 = *(const float4*)&xs_t[(k4+1)*12]; x1 = *(const float4*)&xs_t[(k4+1)*12+4];
        a0.x += w4.y*x0.x; a0.y += w4.y*x0.y; a0.z += w4.y*x0.z; a0.w += w4.y*x0.w;
        a1.x += w4.y*x1.x; a1.y += w4.y*x1.y; a1.z += w4.y*x1.z; a1.w += w4.y*x1.w;
        x0 = *(const float4*)&xs_t[(k4+2)*12]; x1 = *(const float4*)&xs_t[(k4+2)*12+4];
        a0.x += w4.z*x0.x; a0.y += w4.z*x0.y; a0.z += w4.z*x0.z; a0.w += w4.z*x0.w;
        a1.x += w4.z*x1.x; a1.y += w4.z*x1.y; a1.z += w4.z*x1.z; a1.w += w4.z*x1.w;
        x0 = *(const float4*)&xs_t[(k4+3)*12]; x1 = *(const float4*)&xs_t[(k4+3)*12+4];
        a0.x += w4.w*x0.x; a0.y += w4.w*x0.y; a0.z += w4.w*x0.z; a0.w += w4.w*x0.w;
        a1.x += w4.w*x1.x; a1.y += w4.w*x1.y; a1.z += w4.w*x1.z; a1.w += w4.w*x1.w;
      }
      float bi = b_ih[tid];
      giL[0*192+tid]=a0.x+bi; giL[1*192+tid]=a0.y+bi; giL[2*192+tid]=a0.z+bi; giL[3*192+tid]=a0.w+bi;
      giL[4*192+tid]=a1.x+bi; giL[5*192+tid]=a1.y+bi; giL[6*192+tid]=a1.z+bi; giL[7*192+tid]=a1.w+bi;
      float4 b0={0,0,0,0}, b1={0,0,0,0};
      const float* wh = &w_hh[tid*MEMD];
      #pragma unroll 2
      for (int k4 = 0; k4 < MEMD; k4 += 4){
        float4 w4 = *(const float4*)&wh[k4];
        float4 x0, x1;
        x0 = *(const float4*)&hs_t[(k4+0)*12]; x1 = *(const float4*)&hs_t[(k4+0)*12+4];
        b0.x += w4.x*x0.x; b0.y += w4.x*x0.y; b0.z += w4.x*x0.z; b0.w += w4.x*x0.w;
        b1.x += w4.x*x1.x; b1.y += w4.x*x1.y; b1.z += w4.x*x1.z; b1.w += w4.x*x1.w;
        x0 = *(const float4*)&hs_t[(k4+1)*12]; x1 = *(const float4*)&hs_t[(k4+1)*12+4];
        b0.x += w4.y*x0.x; b0.y += w4.y*x0.y; b0.z += w4.y*x0.z; b0.w += w4.y*x0.w;
        b1.x += w4.y*x1.x; b1.y += w4.y*x1.y; b1.z += w4.y*x1.z; b1.w += w4.y*x1.w;
        x0 = *(const float4*)&hs_t[(k4+2)*12]; x1 = *(const float4*)&hs_t[(k4+2)*12+4];
        b0.x += w4.z*x0.x; b0.y += w4.z*x0.y; b0.z += w4.z*x0.z; b0.w += w4.z*x0.w;
        b1.x += w4.z*x1.x; b1.y += w4.z*x1.y; b1.z += w4.z*x1.z; b1.w += w4.z*x1.w;
        x0 = *(const float4*)&hs_t[(k4+3)*12]; x1 = *(const float4*)&hs_t[(k4+3)*12+4];
        b0.x += w4.w*x0.x; b0.y += w4.w*x0.y; b0.z += w4.w*x0.z; b0.w += w4.w*x0.w;
        b1.x += w4.w*x1.x; b1.y += w4.w*x1.y; b1.z += w4.w*x1.z; b1.w += w4.w*x1.w;
      }
      float bh = b_hh[tid];
      ghL[0*192+tid]=b0.x+bh; ghL[1*192+tid]=b0.y+bh; ghL[2*192+tid]=b0.z+bh; ghL[3*192+tid]=b0.w+bh;
      ghL[4*192+tid]=b1.x+bh; ghL[5*192+tid]=b1.y+bh; ghL[6*192+tid]=b1.z+bh; ghL[7*192+tid]=b1.w+bh;
    }
    __syncthreads();
    int cw = tid >> 6, col = tid & 63;
    for (int t = cw; t < 8; t += 4){
      float h = hs_t[col*12 + t];
      float outv;
      int m = mode[t];
      if (m == 0) outv = h;
      else {
        float r  = sigmoidf(giL[t*192+col]      + ghL[t*192+col]);
        float z  = sigmoidf(giL[t*192+64+col]   + ghL[t*192+64+col]);
        float ng = tanhf  (giL[t*192+128+col] + r*ghL[t*192+128+col]);
        outv = (1.f - z)*ng + z*h;
      }
      mem_new[(base+t)*MEMD + col] = outv;
    }
  } else {
    // ---- edge attr GEMM: 64 edges/block ----
    float* ea_t = smem;               // [EE_CH][68]
    float* wls  = smem + EE_CH*68;    // [EE_CH][64]
    int ebase = (blockIdx.x - 512) * 64;
    int ee = tid & 63, qq = tid >> 6;
    int j = ebase + ee;
    int eid = edge_ids[j];
    float rel = edge_ts[j] - last_update[eid];
    int tr = tid >> 4, tc = tid & 15;
    float4 acc[4];
    #pragma unroll
    for (int i=0;i<4;i++) acc[i] = (float4){0.f,0.f,0.f,0.f};
    for (int kc = 0; kc < 2; kc++){
      #pragma unroll 5
      for (int m = 0; m < 20; m++){
        int kk = qq*20 + m;
        int k  = kc*EE_CH + kk;
        float v = (k < TENC) ? cosf(rel*time_w[k] + time_b[k])
                             : edge_features[eid*EEMB + (k - TENC)];
        ea_t[kk*68 + ee] = v;
      }
      #pragma unroll
      for (int it = 0; it < 5; it++){
        int idx = tid + it*256;
        int kk = idx >> 4, c4 = (idx & 15) * 4;
        *(float4*)&wls[kk*64 + c4] = *(const float4*)&WeT[(kc*EE_CH + kk)*64 + c4];
      }
      __syncthreads();
      #pragma unroll 4
      for (int kk = 0; kk < EE_CH; kk++){
        float4 ev = *(const float4*)&ea_t[kk*68 + tr*4];
        float4 wv = *(const float4*)&wls[kk*64 + tc*4];
        acc[0].x += ev.x*wv.x; acc[0].y += ev.x*wv.y; acc[0].z += ev.x*wv.z; acc[0].w += ev.x*wv.w;
        acc[1].x += ev.y*wv.x; acc[1].y += ev.y*wv.y; acc[1].z += ev.y*wv.z; acc[1].w += ev.y*wv.w;
        acc[2].x += ev.z*wv.x; acc[2].y += ev.z*wv.y; acc[2].z += ev.z*wv.z; acc[2].w += ev.z*wv.w;
        acc[3].x += ev.w*wv.x; acc[3].y += ev.w*wv.y; acc[3].z += ev.w*wv.z; acc[3].w += ev.w*wv.w;
      }
      __syncthreads();
    }
    #pragma unroll
    for (int i=0;i<4;i++)
      *(float4*)&ebuf[(ebase + tr*4 + i)*OUTD + tc*4] = acc[i];
  }
}

// ---- qkvs GEMM (LDS-resident, 512 blocks): skip written directly to d_out ----
__global__ __launch_bounds__(256) void k_qkvs(const int* node_ids, const float* node_feat,
                                              const float* mem_new, const float* WcatT,
                                              const float* bcat, float* qbuf, float* kbuf,
                                              float* vbuf, float* outbuf){
  __shared__ float smem[QK_CH*68 + QK_CH*64];   // 12672 floats = 50.7 KB
  float* xs_t = smem;
  float* wls  = smem + QK_CH*68;
  int tid = threadIdx.x;
  int rg = blockIdx.x >> 2, cgx = blockIdx.x & 3;
  int rbase = rg * 64;
  int rr = tid & 63, qq = tid >> 6;
  int nid = node_ids[rbase + rr];
  int tr = tid >> 4, tc = tid & 15;
  float4 acc[4];
  #pragma unroll
  for (int i=0;i<4;i++) acc[i] = (float4){0.f,0.f,0.f,0.f};
  for (int kc = 0; kc < 2; kc++){
    #pragma unroll 6
    for (int m = 0; m < 24; m++){
      int kk = qq*24 + m;
      int k  = kc*QK_CH + kk;
      float v = (k < EEMB) ? node_feat[nid*EEMB + k] : mem_new[nid*MEMD + (k-EEMB)];
      xs_t[kk*68 + rr] = v;
    }
    #pragma unroll
    for (int it = 0; it < 6; it++){
      int idx = tid + it*256;
      int kk = idx >> 4, c4 = (idx & 15) * 4;
      *(float4*)&wls[kk*64 + c4] = *(const float4*)&WcatT[(kc*QK_CH + kk)*256 + cgx*64 + c4];
    }
    __syncthreads();
    #pragma unroll 4
    for (int kk = 0; kk < QK_CH; kk++){
      float4 xv = *(const float4*)&xs_t[kk*68 + tr*4];
      float4 wv = *(const float4*)&wls[kk*64 + tc*4];
      acc[0].x += xv.x*wv.x; acc[0].y += xv.x*wv.y; acc[0].z += xv.x*wv.z; acc[0].w += xv.x*wv.w;
      acc[1].x += xv.y*wv.x; acc[1].y += xv.y*wv.y; acc[1].z += xv.y*wv.z; acc[1].w += xv.y*wv.w;
      acc[2].x += xv.z*wv.x; acc[2].y += xv.z*wv.y; acc[2].z += xv.z*wv.z; acc[2].w += xv.z*wv.w;
      acc[3].x += xv.w*wv.x; acc[3].y += xv.w*wv.y; acc[3].z += xv.w*wv.z; acc[3].w += xv.w*wv.w;
    }
    __syncthreads();
  }
  float4 b4 = *(const float4*)&bcat[cgx*64 + tc*4];
  float* dst = (cgx==0)? qbuf : (cgx==1)? kbuf : (cgx==2)? vbuf : outbuf;
  #pragma unroll
  for (int i=0;i<4;i++){
    float4 o = {acc[i].x+b4.x, acc[i].y+b4.y, acc[i].z+b4.z, acc[i].w+b4.w};
    *(float4*)&dst[(rbase + tr*4 + i)*OUTD + tc*4] = o;
  }
}

// ---- single-pass attention: score -> exp -> accumulate unnormalized num/den.
//      1024 blocks x 4 waves x 4 edges. Row-0 -> per-block partials (no chain). ----
__global__ __launch_bounds__(256) void k_att(const int* edge_index, const int* first_pos,
                                             const float* qbuf, const float* kbuf,
                                             const float* vbuf, const float* ebuf,
                                             float* num, float* den,
                                             float* out0part, float* den0part){
  __shared__ float acc0[4][64];
  __shared__ float sdw[4];
  int tid = threadIdx.x;
  int w = tid >> 6, c = tid & 63;
  float a0 = 0.f, pden = 0.f;
  #pragma unroll
  for (int u = 0; u < 4; u++){
    int j = blockIdx.x*16 + w*4 + u;
    int b = j >> 11, e = j & (NEDGE-1);
    int vsrc = edge_index[b*2*NEDGE + e];
    int vtgt = edge_index[b*2*NEDGE + NEDGE + e];
    int fs = first_pos[vsrc]; if (fs == 0x7FFFFFFF) fs = 0;
    int ft = first_pos[vtgt]; if (ft == 0x7FFFFFFF) ft = 0;
    float ej = ebuf[j*OUTD + c];
    float partial = qbuf[ft*OUTD + c] * (kbuf[fs*OUTD + c] + ej);
    #pragma unroll
    for (int off = 32; off > 0; off >>= 1) partial += __shfl_down(partial, off, 64);
    float sc = __shfl(partial, 0, 64);
    float pe = expf(sc * 0.125f);       // softmax shift-invariant; scores O(0.1)
    float ve = vbuf[fs*OUTD + c] + ej;
    if (ft == 0){ a0 += pe*ve; pden += pe; }              // wave-uniform branch
    else {
      atomicAdd(&num[ft*OUTD + c], pe*ve);
      if (c == 0) atomicAdd(&den[ft], pe);
    }
  }
  acc0[w][c] = a0;
  if (c == 0) sdw[w] = pden;
  __syncthreads();
  if (w == 0){
    out0part[blockIdx.x*64 + c] = acc0[0][c]+acc0[1][c]+acc0[2][c]+acc0[3][c];
    if (c == 0) den0part[blockIdx.x] = sdw[0]+sdw[1]+sdw[2]+sdw[3];
  }
}

// ---- normalize: out += num/den (rows 1..); block 512 reduces row-0 partials ----
__global__ __launch_bounds__(256) void k_norm(const float* num, const float* den,
                                              const float* out0part, const float* den0part,
                                              float* out){
  int tid = threadIdx.x;
  if (blockIdx.x < 512){
    int r = blockIdx.x*16 + (tid >> 4);
    int c4 = (tid & 15) * 4;
    if (r > 0){
      float d = den[r];
      if (d > 0.f){
        float rinv = 1.f / d;
        float4 n4 = *(const float4*)&num[r*64 + c4];
        float4 o4 = *(const float4*)&out[r*64 + c4];
        o4.x += n4.x*rinv; o4.y += n4.y*rinv; o4.z += n4.z*rinv; o4.w += n4.w*rinv;
        *(float4*)&out[r*64 + c4] = o4;
      }
    }
  } else {
    __shared__ float part[4][64];
    __shared__ float dred[4];
    __shared__ float s_den0;
    int g = tid >> 6, c = tid & 63;
    float s = 0.f;
    for (int j = g*256; j < g*256 + 256; j++) s += out0part[j*64 + c];
    part[g][c] = s;
    float dd = den0part[tid] + den0part[tid+256] + den0part[tid+512] + den0part[tid+768];
    #pragma unroll
    for (int off = 32; off > 0; off >>= 1) dd += __shfl_down(dd, off, 64);
    if (c == 0) dred[g] = dd;
    __syncthreads();
    if (tid == 0) s_den0 = dred[0]+dred[1]+dred[2]+dred[3];
    __syncthreads();
    if (g == 0){
      float den0 = s_den0;
      if (den0 > 0.f)
        out[c] += (part[0][c]+part[1][c]+part[2][c]+part[3][c]) / den0;
    }
  }
}

extern "C" void kernel_launch(void* const* d_in, const int* in_sizes, int n_in,
                              void* d_out, int out_size, void* d_ws, size_t ws_size,
                              hipStream_t stream){
  const int*   ev_type      = (const int*)  d_in[0];
  const int*   src_ids      = (const int*)  d_in[1];
  const float* src_mask     = (const float*)d_in[2];
  const int*   dst_ids      = (const int*)  d_in[3];
  const float* dst_mask     = (const float*)d_in[4];
  const int*   ev_edge      = (const int*)  d_in[5];
  const float* ev_emb       = (const float*)d_in[6];
  const float* ev_ts        = (const float*)d_in[7];
  const int*   node_ids     = (const int*)  d_in[8];
  const int*   edge_ids     = (const int*)  d_in[9];
  const int*   edge_index   = (const int*)  d_in[10];
  const float* edge_ts      = (const float*)d_in[11];
  const float* memory       = (const float*)d_in[12];
  const float* last_update  = (const float*)d_in[13];
  const float* node_feat    = (const float*)d_in[14];
  const float* edge_feat    = (const float*)d_in[15];
  const float* type_emb     = (const float*)d_in[16];
  const float* time_w       = (const float*)d_in[17];
  const float* time_b       = (const float*)d_in[18];
  const float* gru_w_ih     = (const float*)d_in[19];
  const float* gru_w_hh     = (const float*)d_in[20];
  const float* gru_b_ih     = (const float*)d_in[21];
  const float* gru_b_hh     = (const float*)d_in[22];
  const float* Wq  = (const float*)d_in[23]; const float* bq    = (const float*)d_in[24];
  const float* Wk  = (const float*)d_in[25]; const float* bk    = (const float*)d_in[26];
  const float* Wv  = (const float*)d_in[27]; const float* bv    = (const float*)d_in[28];
  const float* We  = (const float*)d_in[29];
  const float* Wsk = (const float*)d_in[30]; const float* bskip = (const float*)d_in[31];
  float* out = (float*)d_out;

  float* ws = (float*)d_ws;
  size_t off = 0;
  // --- zeroed span (accumulators) ---
  float* agg_src = ws + off; off += (size_t)MAXN*MSG;
  float* agg_dst = ws + off; off += (size_t)MAXN*MSG;
  int* cnt_src   = (int*)(ws + off); off += MAXN;
  int* cnt_dst   = (int*)(ws + off); off += MAXN;
  int* present_s = (int*)(ws + off); off += MAXN;
  int* present_d = (int*)(ws + off); off += MAXN;
  float* den     = ws + off; off += BN;
  float* num     = ws + off; off += (size_t)BN*OUTD;
  int n_zero = (int)off;
  // --- rest (fully overwritten each call) ---
  int* first_pos = (int*)(ws + off); off += MAXN;
  float* mem_new = ws + off; off += (size_t)MAXN*MEMD;
  float* qbuf    = ws + off; off += (size_t)BN*OUTD;
  float* kbuf    = ws + off; off += (size_t)BN*OUTD;
  float* vbuf    = ws + off; off += (size_t)BN*OUTD;
  float* ebuf    = ws + off; off += (size_t)BE*OUTD;
  float* den0part= ws + off; off += 1024;
  float* out0part= ws + off; off += 1024*64;
  float* WcatT   = ws + off; off += (size_t)INGNN*256;
  float* WeT     = ws + off; off += (size_t)EDIM*64;
  float* bcat    = ws + off; off += 256;

  k_init<<<2048, 256, 0, stream>>>(ws, n_zero, first_pos,
                                   Wq, Wk, Wv, Wsk, We, bq, bk, bv, bskip,
                                   WcatT, WeT, bcat);
  k_msg_first<<<SS + (BN + 319)/320, 320, 0, stream>>>(
      ev_type, src_ids, src_mask, dst_ids, dst_mask, ev_edge,
      ev_emb, ev_ts, memory, last_update, type_emb, time_w, time_b,
      agg_src, agg_dst, cnt_src, cnt_dst,
      node_ids, first_pos, present_s, present_d);
  k_gru_edge<<<768, 256, 0, stream>>>(agg_src, agg_dst, cnt_src, cnt_dst,
                                      present_s, present_d, memory,
                                      gru_w_ih, gru_w_hh, gru_b_ih, gru_b_hh, mem_new,
                                      edge_ids, edge_ts, last_update, edge_feat,
                                      time_w, time_b, WeT, ebuf);
  k_qkvs<<<512, 256, 0, stream>>>(node_ids, node_feat, mem_new, WcatT, bcat,
                                  qbuf, kbuf, vbuf, out);
  k_att<<<1024, 256, 0, stream>>>(edge_index, first_pos, qbuf, kbuf, vbuf, ebuf,
                                  num, den, out0part, den0part);
  k_norm<<<513, 256, 0, stream>>>(num, den, out0part, den0part, out);
}

// Round 14
// 78.162 us; speedup vs baseline: 1.1557x; 1.0107x over previous
//
#include <hip/hip_runtime.h>
#include <math.h>

// ---- problem dims ----
#define BB 8
#define SS 512
#define NEDGE 2048
#define MAXN 4096
#define TYPED 16
#define MEMD 64
#define TENC 32
#define EEMB 128
#define OUTD 64
#define MSG 304      // 16+64+64+32+128
#define INGNN 192    // 128+64
#define EDIM 160     // 32+128
#define BN 8192      // B*N
#define BE 16384     // B*E
#define QK_CH 96
#define EE_CH 80

__device__ __forceinline__ float sigmoidf(float x){ return 1.f/(1.f + expf(-x)); }

// ---- init: zero small accumulator span + batch-0-touched agg rows only,
//      first_pos=INT_MAX, W transposes ----
__global__ void k_init(float* zero_base, int n_zero, int* first_pos,
                       const int* src_ids, const int* dst_ids,
                       float* agg_src, float* agg_dst,
                       const float* Wq, const float* Wk, const float* Wv,
                       const float* Wskip, const float* We,
                       const float* bq, const float* bk,
                       const float* bv, const float* bskip,
                       float* WcatT, float* WeT, float* bcat){
  int i = blockIdx.x*blockDim.x + threadIdx.x;
  int stride = gridDim.x*blockDim.x;
  float4* z4 = (float4*)zero_base;
  int n4 = n_zero >> 2;
  float4 zero = {0.f,0.f,0.f,0.f};
  for (int t=i; t<n4; t+=stride) z4[t] = zero;
  for (int t=i; t<MAXN; t+=stride) first_pos[t] = 0x7FFFFFFF;
  // zero only agg rows touched by batch-0 events (duplicates benign: all write 0)
  for (int t=i; t<2*SS*MSG; t+=stride){
    int s = t / (2*MSG);
    int rem = t - s*2*MSG;
    if (rem < MSG) agg_src[src_ids[s]*MSG + rem] = 0.f;
    else           agg_dst[dst_ids[s]*MSG + (rem-MSG)] = 0.f;
  }
  int j = i;
  if (j < 4*64*192){
    int o = j/(64*192); int rem = j%(64*192); int q=rem/192, k=rem%192;
    const float* W = (o==0)?Wq:(o==1)?Wk:(o==2)?Wv:Wskip;
    WcatT[k*256 + o*64 + q] = W[rem];
  } else {
    j -= 4*64*192;
    if (j < 64*EDIM){ int q=j/EDIM, k=j%EDIM; WeT[k*64+q] = We[j]; }
    else {
      j -= 64*EDIM;
      if (j < 256){
        const float* b = (j<64)?bq:(j<128)?bk:(j<192)?bv:bskip;
        bcat[j] = b[j&63];
      }
    }
  }
}

// ---- fused: messages for batch 0 (blocks < SS) + first-pos/presence (rest) ----
__global__ void k_msg_first(const int* ev_type, const int* src_ids, const float* src_mask,
                            const int* dst_ids, const float* dst_mask, const int* ev_edge,
                            const float* ev_emb, const float* ev_ts, const float* memory,
                            const float* last_update, const float* type_emb,
                            const float* time_w, const float* time_b,
                            float* agg_src, float* agg_dst, int* cnt_src, int* cnt_dst,
                            const int* node_ids, int* first_pos, int* ps, int* pd){
  int bb = blockIdx.x;
  if (bb < SS){
    int s = bb;
    int et = ev_type[s];
    int sid = src_ids[s], did = dst_ids[s];
    float sm = src_mask[s], dm = dst_mask[s];
    float ts = ev_ts[s];
    float ns = (et >= 3) ? 1.f : 0.f;
    float ine = (et == 3 || et == 4) ? 1.f : 0.f;
    float rel = ts - last_update[ev_edge[s]] * dm;
    float tin = ts*ine + rel*dm;
    int d = threadIdx.x;
    if (d < MSG){
      float vs, vd;
      if (d < TYPED){ float t = type_emb[et*TYPED + d]; vs = t; vd = t; }
      else if (d < 80){ int c=d-16;  vs = memory[sid*MEMD+c]*sm; vd = memory[did*MEMD+c]*dm; }
      else if (d < 144){ int c=d-80; vs = memory[did*MEMD+c]*dm; vd = memory[sid*MEMD+c]*sm; }
      else if (d < 176){ int c=d-144; float ce = cosf(tin*time_w[c]+time_b[c])*ns; vs=ce; vd=ce; }
      else { float e = ev_emb[s*EEMB + (d-176)]; vs=e; vd=e; }
      atomicAdd(&agg_src[sid*MSG+d], vs*ns);
      atomicAdd(&agg_dst[did*MSG+d], vd*dm);
    }
    if (d == MSG){ atomicAdd(&cnt_src[sid], 1); atomicAdd(&cnt_dst[did], 1); }
  } else {
    int i = (bb - SS)*320 + threadIdx.x;
    if (i < BN) atomicMin(&first_pos[node_ids[i]], i);
    if (i < BB*SS){ ps[src_ids[i]] = 1; pd[dst_ids[i]] = 1; }
  }
}

// ---- fused GRU (blocks 0..511) || edge GEMM (blocks 512..767) ----
__global__ __launch_bounds__(256) void k_gru_edge(
    const float* agg_src, const float* agg_dst, const int* cnt_src, const int* cnt_dst,
    const int* ps, const int* pd, const float* memory,
    const float* w_ih, const float* w_hh, const float* b_ih, const float* b_hh,
    float* mem_new,
    const int* edge_ids, const float* edge_ts, const float* last_update,
    const float* edge_features, const float* time_w, const float* time_b,
    const float* WeT, float* ebuf){
  __shared__ float smem[EE_CH*68 + EE_CH*64];   // 10560 floats = 42.2 KB (max of both uses)
  int tid = threadIdx.x;
  if (blockIdx.x < 512){
    // ---- GRU: 8 nodes/block ----
    float* xs_t = smem;                 // [MSG][12]
    float* hs_t = smem + 3648;          // [MEMD][12]
    float* giL  = smem + 4416;          // [8][192]
    float* ghL  = smem + 5952;          // [8][192]
    int*   mode = (int*)(smem + 7488);  // [8]
    int*   cnt8 = (int*)(smem + 7496);  // [8]
    float* rcnt = smem + 7504;          // [8]
    int base = blockIdx.x * 8;
    if (tid < 8){
      int n = base + tid;
      int m = pd[n] ? 2 : (ps[n] ? 1 : 0);
      mode[tid] = m;
      int c = (m==2) ? cnt_dst[n] : ((m==1) ? cnt_src[n] : 0);
      cnt8[tid] = c;
      rcnt[tid] = 1.f / (float)max(c, 1);
    }
    __syncthreads();
    for (int idx = tid; idx < 8*MSG; idx += 256){
      int t = idx / MSG, k = idx - t*MSG;
      // guard: unzeroed agg rows are only read when cnt>0 (zeroed in k_init)
      float x = 0.f;
      if (cnt8[t] > 0){
        const float* agg = (mode[t]==2) ? agg_dst : agg_src;
        x = agg[(base+t)*MSG + k] * rcnt[t];
      }
      xs_t[k*12 + t] = x;
    }
    for (int idx = tid; idx < 8*MEMD; idx += 256){
      int t = idx / MEMD, k = idx - t*MEMD;
      hs_t[k*12 + t] = memory[(base+t)*MEMD + k];
    }
    __syncthreads();
    if (tid < 192){
      float4 a0={0,0,0,0}, a1={0,0,0,0};
      const float* wr = &w_ih[tid*MSG];
      #pragma unroll 2
      for (int k4 = 0; k4 < MSG; k4 += 4){
        float4 w4 = *(const float4*)&wr[k4];
        float4 x0, x1;
        x0 = *(const float4*)&xs_t[(k4+0)*12]; x1 = *(const float4*)&xs_t[(k4+0)*12+4];
        a0.x += w4.x*x0.x; a0.y += w4.x*x0.y; a0.z += w4.x*x0.z; a0.w += w4.x*x0.w;
        a1.x += w4.x*x1.x; a1.y += w4.x*x1.y; a1.z += w4.x*x1.z; a1.w += w4.x*x1.w;
        x0 = *(const float4*)&xs_t[(k4+1)*12]; x1 = *(const float4*)&xs_t[(k4+1)*12+4];
        a0.x += w4.y*x0.x; a0.y += w4.y*x0.y; a0.z += w4.y*x0.z; a0.w += w4.y*x0.w;
        a1.x += w4.y*x1.x; a1.y += w4.y*x1.y; a1.z += w4.y*x1.z; a1.w += w4.y*x1.w;
        x0 = *(const float4*)&xs_t[(k4+2)*12]; x1 = *(const float4*)&xs_t[(k4+2)*12+4];
        a0.x += w4.z*x0.x; a0.y += w4.z*x0.y; a0.z += w4.z*x0.z; a0.w += w4.z*x0.w;
        a1.x += w4.z*x1.x; a1.y += w4.z*x1.y; a1.z += w4.z*x1.z; a1.w += w4.z*x1.w;
        x0 = *(const float4*)&xs_t[(k4+3)*12]; x1 = *(const float4*)&xs_t[(k4+3)*12+4];
        a0.x += w4.w*x0.x; a0.y += w4.w*x0.y; a0.z += w4.w*x0.z; a0.w += w4.w*x0.w;
        a1.x += w4.w*x1.x; a1.y += w4.w*x1.y; a1.z += w4.w*x1.z; a1.w += w4.w*x1.w;
      }
      float bi = b_ih[tid];
      giL[0*192+tid]=a0.x+bi; giL[1*192+tid]=a0.y+bi; giL[2*192+tid]=a0.z+bi; giL[3*192+tid]=a0.w+bi;
      giL[4*192+tid]=a1.x+bi; giL[5*192+tid]=a1.y+bi; giL[6*192+tid]=a1.z+bi; giL[7*192+tid]=a1.w+bi;
      float4 b0={0,0,0,0}, b1={0,0,0,0};
      const float* wh = &w_hh[tid*MEMD];
      #pragma unroll 2
      for (int k4 = 0; k4 < MEMD; k4 += 4){
        float4 w4 = *(const float4*)&wh[k4];
        float4 x0, x1;
        x0 = *(const float4*)&hs_t[(k4+0)*12]; x1 = *(const float4*)&hs_t[(k4+0)*12+4];
        b0.x += w4.x*x0.x; b0.y += w4.x*x0.y; b0.z += w4.x*x0.z; b0.w += w4.x*x0.w;
        b1.x += w4.x*x1.x; b1.y += w4.x*x1.y; b1.z += w4.x*x1.z; b1.w += w4.x*x1.w;
        x0 = *(const float4*)&hs_t[(k4+1)*12]; x1 = *(const float4*)&hs_t[(k4+1)*12+4];
        b0.x += w4.y*x0.x; b0.y += w4.y*x0.y; b0.z += w4.y*x0.z; b0.w += w4.y*x0.w;
        b1.x += w4.y*x1.x; b1.y += w4.y*x1.y; b1.z += w4.y*x1.z; b1.w += w4.y*x1.w;
        x0 = *(const float4*)&hs_t[(k4+2)*12]; x1 = *(const float4*)&hs_t[(k4+2)*12+4];
        b0.x += w4.z*x0.x; b0.y += w4.z*x0.y; b0.z += w4.z*x0.z; b0.w += w4.z*x0.w;
        b1.x += w4.z*x1.x; b1.y += w4.z*x1.y; b1.z += w4.z*x1.z; b1.w += w4.z*x1.w;
        x0 = *(const float4*)&hs_t[(k4+3)*12]; x1 = *(const float4*)&hs_t[(k4+3)*12+4];
        b0.x += w4.w*x0.x; b0.y += w4.w*x0.y; b0.z += w4.w*x0.z; b0.w += w4.w*x0.w;
        b1.x += w4.w*x1.x; b1.y += w4.w*x1.y; b1.z += w4.w*x1.z; b1.w += w4.w*x1.w;
      }
      float bh = b_hh[tid];
      ghL[0*192+tid]=b0.x+bh; ghL[1*192+tid]=b0.y+bh; ghL[2*192+tid]=b0.z+bh; ghL[3*192+tid]=b0.w+bh;
      ghL[4*192+tid]=b1.x+bh; ghL[5*192+tid]=b1.y+bh; ghL[6*192+tid]=b1.z+bh; ghL[7*192+tid]=b1.w+bh;
    }
    __syncthreads();
    int cw = tid >> 6, col = tid & 63;
    for (int t = cw; t < 8; t += 4){
      float h = hs_t[col*12 + t];
      float outv;
      int m = mode[t];
      if (m == 0) outv = h;
      else {
        float r  = sigmoidf(giL[t*192+col]      + ghL[t*192+col]);
        float z  = sigmoidf(giL[t*192+64+col]   + ghL[t*192+64+col]);
        float ng = tanhf  (giL[t*192+128+col] + r*ghL[t*192+128+col]);
        outv = (1.f - z)*ng + z*h;
      }
      mem_new[(base+t)*MEMD + col] = outv;
    }
  } else {
    // ---- edge attr GEMM: 64 edges/block ----
    float* ea_t = smem;               // [EE_CH][68]
    float* wls  = smem + EE_CH*68;    // [EE_CH][64]
    int ebase = (blockIdx.x - 512) * 64;
    int ee = tid & 63, qq = tid >> 6;
    int j = ebase + ee;
    int eid = edge_ids[j];
    float rel = edge_ts[j] - last_update[eid];
    int tr = tid >> 4, tc = tid & 15;
    float4 acc[4];
    #pragma unroll
    for (int i=0;i<4;i++) acc[i] = (float4){0.f,0.f,0.f,0.f};
    for (int kc = 0; kc < 2; kc++){
      #pragma unroll 5
      for (int m = 0; m < 20; m++){
        int kk = qq*20 + m;
        int k  = kc*EE_CH + kk;
        float v = (k < TENC) ? cosf(rel*time_w[k] + time_b[k])
                             : edge_features[eid*EEMB + (k - TENC)];
        ea_t[kk*68 + ee] = v;
      }
      #pragma unroll
      for (int it = 0; it < 5; it++){
        int idx = tid + it*256;
        int kk = idx >> 4, c4 = (idx & 15) * 4;
        *(float4*)&wls[kk*64 + c4] = *(const float4*)&WeT[(kc*EE_CH + kk)*64 + c4];
      }
      __syncthreads();
      #pragma unroll 4
      for (int kk = 0; kk < EE_CH; kk++){
        float4 ev = *(const float4*)&ea_t[kk*68 + tr*4];
        float4 wv = *(const float4*)&wls[kk*64 + tc*4];
        acc[0].x += ev.x*wv.x; acc[0].y += ev.x*wv.y; acc[0].z += ev.x*wv.z; acc[0].w += ev.x*wv.w;
        acc[1].x += ev.y*wv.x; acc[1].y += ev.y*wv.y; acc[1].z += ev.y*wv.z; acc[1].w += ev.y*wv.w;
        acc[2].x += ev.z*wv.x; acc[2].y += ev.z*wv.y; acc[2].z += ev.z*wv.z; acc[2].w += ev.z*wv.w;
        acc[3].x += ev.w*wv.x; acc[3].y += ev.w*wv.y; acc[3].z += ev.w*wv.z; acc[3].w += ev.w*wv.w;
      }
      __syncthreads();
    }
    #pragma unroll
    for (int i=0;i<4;i++)
      *(float4*)&ebuf[(ebase + tr*4 + i)*OUTD + tc*4] = acc[i];
  }
}

// ---- qkvs GEMM (LDS-resident, 512 blocks): skip written directly to d_out ----
__global__ __launch_bounds__(256) void k_qkvs(const int* node_ids, const float* node_feat,
                                              const float* mem_new, const float* WcatT,
                                              const float* bcat, float* qbuf, float* kbuf,
                                              float* vbuf, float* outbuf){
  __shared__ float smem[QK_CH*68 + QK_CH*64];   // 12672 floats = 50.7 KB
  float* xs_t = smem;
  float* wls  = smem + QK_CH*68;
  int tid = threadIdx.x;
  int rg = blockIdx.x >> 2, cgx = blockIdx.x & 3;
  int rbase = rg * 64;
  int rr = tid & 63, qq = tid >> 6;
  int nid = node_ids[rbase + rr];
  int tr = tid >> 4, tc = tid & 15;
  float4 acc[4];
  #pragma unroll
  for (int i=0;i<4;i++) acc[i] = (float4){0.f,0.f,0.f,0.f};
  for (int kc = 0; kc < 2; kc++){
    #pragma unroll 6
    for (int m = 0; m < 24; m++){
      int kk = qq*24 + m;
      int k  = kc*QK_CH + kk;
      float v = (k < EEMB) ? node_feat[nid*EEMB + k] : mem_new[nid*MEMD + (k-EEMB)];
      xs_t[kk*68 + rr] = v;
    }
    #pragma unroll
    for (int it = 0; it < 6; it++){
      int idx = tid + it*256;
      int kk = idx >> 4, c4 = (idx & 15) * 4;
      *(float4*)&wls[kk*64 + c4] = *(const float4*)&WcatT[(kc*QK_CH + kk)*256 + cgx*64 + c4];
    }
    __syncthreads();
    #pragma unroll 4
    for (int kk = 0; kk < QK_CH; kk++){
      float4 xv = *(const float4*)&xs_t[kk*68 + tr*4];
      float4 wv = *(const float4*)&wls[kk*64 + tc*4];
      acc[0].x += xv.x*wv.x; acc[0].y += xv.x*wv.y; acc[0].z += xv.x*wv.z; acc[0].w += xv.x*wv.w;
      acc[1].x += xv.y*wv.x; acc[1].y += xv.y*wv.y; acc[1].z += xv.y*wv.z; acc[1].w += xv.y*wv.w;
      acc[2].x += xv.z*wv.x; acc[2].y += xv.z*wv.y; acc[2].z += xv.z*wv.z; acc[2].w += xv.z*wv.w;
      acc[3].x += xv.w*wv.x; acc[3].y += xv.w*wv.y; acc[3].z += xv.w*wv.z; acc[3].w += xv.w*wv.w;
    }
    __syncthreads();
  }
  float4 b4 = *(const float4*)&bcat[cgx*64 + tc*4];
  float* dst = (cgx==0)? qbuf : (cgx==1)? kbuf : (cgx==2)? vbuf : outbuf;
  #pragma unroll
  for (int i=0;i<4;i++){
    float4 o = {acc[i].x+b4.x, acc[i].y+b4.y, acc[i].z+b4.z, acc[i].w+b4.w};
    *(float4*)&dst[(rbase + tr*4 + i)*OUTD + tc*4] = o;
  }
}

// ---- single-pass attention (restrict-qualified so index loads hoist past atomics) ----
__global__ __launch_bounds__(256) void k_att(const int* __restrict__ edge_index,
                                             const int* __restrict__ first_pos,
                                             const float* __restrict__ qbuf,
                                             const float* __restrict__ kbuf,
                                             const float* __restrict__ vbuf,
                                             const float* __restrict__ ebuf,
                                             float* __restrict__ num,
                                             float* __restrict__ den,
                                             float* __restrict__ out0part,
                                             float* __restrict__ den0part){
  __shared__ float acc0[4][64];
  __shared__ float sdw[4];
  int tid = threadIdx.x;
  int w = tid >> 6, c = tid & 63;
  // hoist all 4 edges' index chains (independent loads issue together)
  int fs4[4], ft4[4];
  #pragma unroll
  for (int u = 0; u < 4; u++){
    int j = blockIdx.x*16 + w*4 + u;
    int b = j >> 11, e = j & (NEDGE-1);
    int vsrc = edge_index[b*2*NEDGE + e];
    int vtgt = edge_index[b*2*NEDGE + NEDGE + e];
    int fs = first_pos[vsrc]; if (fs == 0x7FFFFFFF) fs = 0;
    int ft = first_pos[vtgt]; if (ft == 0x7FFFFFFF) ft = 0;
    fs4[u] = fs; ft4[u] = ft;
  }
  float a0 = 0.f, pden = 0.f;
  #pragma unroll
  for (int u = 0; u < 4; u++){
    int j = blockIdx.x*16 + w*4 + u;
    int fs = fs4[u], ft = ft4[u];
    float ej = ebuf[j*OUTD + c];
    float partial = qbuf[ft*OUTD + c] * (kbuf[fs*OUTD + c] + ej);
    #pragma unroll
    for (int off = 32; off > 0; off >>= 1) partial += __shfl_down(partial, off, 64);
    float sc = __shfl(partial, 0, 64);
    float pe = expf(sc * 0.125f);       // softmax shift-invariant; scores O(0.1)
    float ve = vbuf[fs*OUTD + c] + ej;
    if (ft == 0){ a0 += pe*ve; pden += pe; }              // wave-uniform branch
    else {
      atomicAdd(&num[ft*OUTD + c], pe*ve);
      if (c == 0) atomicAdd(&den[ft], pe);
    }
  }
  acc0[w][c] = a0;
  if (c == 0) sdw[w] = pden;
  __syncthreads();
  if (w == 0){
    out0part[blockIdx.x*64 + c] = acc0[0][c]+acc0[1][c]+acc0[2][c]+acc0[3][c];
    if (c == 0) den0part[blockIdx.x] = sdw[0]+sdw[1]+sdw[2]+sdw[3];
  }
}

// ---- normalize: out += num/den (rows 1..); block 512 reduces row-0 partials ----
__global__ __launch_bounds__(256) void k_norm(const float* num, const float* den,
                                              const float* out0part, const float* den0part,
                                              float* out){
  int tid = threadIdx.x;
  if (blockIdx.x < 512){
    int r = blockIdx.x*16 + (tid >> 4);
    int c4 = (tid & 15) * 4;
    if (r > 0){
      float d = den[r];
      if (d > 0.f){
        float rinv = 1.f / d;
        float4 n4 = *(const float4*)&num[r*64 + c4];
        float4 o4 = *(const float4*)&out[r*64 + c4];
        o4.x += n4.x*rinv; o4.y += n4.y*rinv; o4.z += n4.z*rinv; o4.w += n4.w*rinv;
        *(float4*)&out[r*64 + c4] = o4;
      }
    }
  } else {
    __shared__ float part[4][64];
    __shared__ float dred[4];
    __shared__ float s_den0;
    int g = tid >> 6, c = tid & 63;
    float s = 0.f;
    for (int j = g*256; j < g*256 + 256; j++) s += out0part[j*64 + c];
    part[g][c] = s;
    float dd = den0part[tid] + den0part[tid+256] + den0part[tid+512] + den0part[tid+768];
    #pragma unroll
    for (int off = 32; off > 0; off >>= 1) dd += __shfl_down(dd, off, 64);
    if (c == 0) dred[g] = dd;
    __syncthreads();
    if (tid == 0) s_den0 = dred[0]+dred[1]+dred[2]+dred[3];
    __syncthreads();
    if (g == 0){
      float den0 = s_den0;
      if (den0 > 0.f)
        out[c] += (part[0][c]+part[1][c]+part[2][c]+part[3][c]) / den0;
    }
  }
}

extern "C" void kernel_launch(void* const* d_in, const int* in_sizes, int n_in,
                              void* d_out, int out_size, void* d_ws, size_t ws_size,
                              hipStream_t stream){
  const int*   ev_type      = (const int*)  d_in[0];
  const int*   src_ids      = (const int*)  d_in[1];
  const float* src_mask     = (const float*)d_in[2];
  const int*   dst_ids      = (const int*)  d_in[3];
  const float* dst_mask     = (const float*)d_in[4];
  const int*   ev_edge      = (const int*)  d_in[5];
  const float* ev_emb       = (const float*)d_in[6];
  const float* ev_ts        = (const float*)d_in[7];
  const int*   node_ids     = (const int*)  d_in[8];
  const int*   edge_ids     = (const int*)  d_in[9];
  const int*   edge_index   = (const int*)  d_in[10];
  const float* edge_ts      = (const float*)d_in[11];
  const float* memory       = (const float*)d_in[12];
  const float* last_update  = (const float*)d_in[13];
  const float* node_feat    = (const float*)d_in[14];
  const float* edge_feat    = (const float*)d_in[15];
  const float* type_emb     = (const float*)d_in[16];
  const float* time_w       = (const float*)d_in[17];
  const float* time_b       = (const float*)d_in[18];
  const float* gru_w_ih     = (const float*)d_in[19];
  const float* gru_w_hh     = (const float*)d_in[20];
  const float* gru_b_ih     = (const float*)d_in[21];
  const float* gru_b_hh     = (const float*)d_in[22];
  const float* Wq  = (const float*)d_in[23]; const float* bq    = (const float*)d_in[24];
  const float* Wk  = (const float*)d_in[25]; const float* bk    = (const float*)d_in[26];
  const float* Wv  = (const float*)d_in[27]; const float* bv    = (const float*)d_in[28];
  const float* We  = (const float*)d_in[29];
  const float* Wsk = (const float*)d_in[30]; const float* bskip = (const float*)d_in[31];
  float* out = (float*)d_out;

  float* ws = (float*)d_ws;
  size_t off = 0;
  // --- zeroed span (small accumulators only; agg rows zeroed selectively) ---
  int* cnt_src   = (int*)(ws + off); off += MAXN;
  int* cnt_dst   = (int*)(ws + off); off += MAXN;
  int* present_s = (int*)(ws + off); off += MAXN;
  int* present_d = (int*)(ws + off); off += MAXN;
  float* den     = ws + off; off += BN;
  float* num     = ws + off; off += (size_t)BN*OUTD;
  int n_zero = (int)off;
  // --- rest ---
  float* agg_src = ws + off; off += (size_t)MAXN*MSG;
  float* agg_dst = ws + off; off += (size_t)MAXN*MSG;
  int* first_pos = (int*)(ws + off); off += MAXN;
  float* mem_new = ws + off; off += (size_t)MAXN*MEMD;
  float* qbuf    = ws + off; off += (size_t)BN*OUTD;
  float* kbuf    = ws + off; off += (size_t)BN*OUTD;
  float* vbuf    = ws + off; off += (size_t)BN*OUTD;
  float* ebuf    = ws + off; off += (size_t)BE*OUTD;
  float* den0part= ws + off; off += 1024;
  float* out0part= ws + off; off += 1024*64;
  float* WcatT   = ws + off; off += (size_t)INGNN*256;
  float* WeT     = ws + off; off += (size_t)EDIM*64;
  float* bcat    = ws + off; off += 256;

  k_init<<<1024, 256, 0, stream>>>(ws, n_zero, first_pos, src_ids, dst_ids,
                                   agg_src, agg_dst,
                                   Wq, Wk, Wv, Wsk, We, bq, bk, bv, bskip,
                                   WcatT, WeT, bcat);
  k_msg_first<<<SS + (BN + 319)/320, 320, 0, stream>>>(
      ev_type, src_ids, src_mask, dst_ids, dst_mask, ev_edge,
      ev_emb, ev_ts, memory, last_update, type_emb, time_w, time_b,
      agg_src, agg_dst, cnt_src, cnt_dst,
      node_ids, first_pos, present_s, present_d);
  k_gru_edge<<<768, 256, 0, stream>>>(agg_src, agg_dst, cnt_src, cnt_dst,
                                      present_s, present_d, memory,
                                      gru_w_ih, gru_w_hh, gru_b_ih, gru_b_hh, mem_new,
                                      edge_ids, edge_ts, last_update, edge_feat,
                                      time_w, time_b, WeT, ebuf);
  k_qkvs<<<512, 256, 0, stream>>>(node_ids, node_feat, mem_new, WcatT, bcat,
                                  qbuf, kbuf, vbuf, out);
  k_att<<<1024, 256, 0, stream>>>(edge_index, first_pos, qbuf, kbuf, vbuf, ebuf,
                                  num, den, out0part, den0part);
  k_norm<<<513, 256, 0, stream>>>(num, den, out0part, den0part, out);
}